// Round 1
// 669.927 us; speedup vs baseline: 1.1403x; 1.1403x over previous
//
#include <hip/hip_runtime.h>
#include <cstdint>
#include <cstddef>

// BitNet b1.58 FFN: x[8192,2048] fp32 -> h[8192,8192] (relu^2) -> out[8192,2048] fp32
// R5: - H stored as saturated int16 relu(acc) (exact; scale applied in quant_h)
//       -> workspace 320->192MB/nchunk -> nchunk 8->4 (CR=2048), H traffic halved
//     - per-row max via int atomicMax in GEMM1 epilogue + tiny scale kernel
//     - GEMM2 BM=64 -> 512 blocks (was 128: 0.5 blocks/CU)
//     - XCD n-slice block remap (B-slice 2MB resident per XCD L2, persists across chunks)
//     - BK=128 with XOR-swizzled LDS (linear global_load_lds dest + pre-swizzled
//       global source + swizzled ds_read; rule-21 both-sides pattern)

typedef int v4i __attribute__((ext_vector_type(4)));
typedef short short8 __attribute__((ext_vector_type(8)));

#define INV_WELEMS (1.0 / 16777216.0)   // 1 / (8192*2048)

__device__ __forceinline__ void async_ld16(const void* g, void* s) {
    __builtin_amdgcn_global_load_lds(
        (const __attribute__((address_space(1))) void*)(uintptr_t)g,
        (__attribute__((address_space(3))) void*)(unsigned int)(uintptr_t)s,
        16, 0, 0);
}

// ---- sum(|w|) over 16.7M fp32, fp64 accumulate ----------------------------
__global__ void absmean_kernel(const float* __restrict__ w,
                               double* __restrict__ acc) {
    __shared__ double red[256];
    int t = threadIdx.x;
    unsigned int tid = blockIdx.x * 256u + t;
    const float4* wv = (const float4*)w;
    float s = 0.f;
#pragma unroll
    for (int i = 0; i < 4; ++i) {
        float4 v = wv[tid + i * 1048576u];
        s += fabsf(v.x) + fabsf(v.y) + fabsf(v.z) + fabsf(v.w);
    }
    red[t] = (double)s;
    __syncthreads();
    for (int o = 128; o > 0; o >>= 1) {
        if (t < o) red[t] += red[t + o];
        __syncthreads();
    }
    if (t == 0) atomicAdd(acc, red[0]);
}

// ---- ternary quantize weights: q = clip(rint(w/gamma), -1, 1) -------------
__global__ void quant_w_kernel(const float* __restrict__ w,
                               int8_t* __restrict__ q,
                               const double* __restrict__ acc) {
    float gamma = (float)(acc[0] * INV_WELEMS + 1e-5);
    unsigned int tid = blockIdx.x * 256u + threadIdx.x;
    const float4* wv = (const float4*)w;
    float4 a = wv[tid * 2];
    float4 b = wv[tid * 2 + 1];
    float f[8] = {a.x, a.y, a.z, a.w, b.x, b.y, b.z, b.w};
    unsigned int lo = 0, hi = 0;
#pragma unroll
    for (int k = 0; k < 4; ++k) {
        int qv = (int)fminf(fmaxf(rintf(f[k] / gamma), -1.f), 1.f);
        lo |= ((unsigned int)(qv & 0xff)) << (8 * k);
    }
#pragma unroll
    for (int k = 0; k < 4; ++k) {
        int qv = (int)fminf(fmaxf(rintf(f[4 + k] / gamma), -1.f), 1.f);
        hi |= ((unsigned int)(qv & 0xff)) << (8 * k);
    }
    uint2 o; o.x = lo; o.y = hi;
    ((uint2*)q)[tid] = o;
}

// ---- per-token int8 quantize of x; c1[row] = gamma1 / s -------------------
__global__ void quant_x_kernel(const float* __restrict__ x,
                               int8_t* __restrict__ qx,
                               float* __restrict__ c1,
                               const double* __restrict__ accw) {
    __shared__ float red[256];
    int t = threadIdx.x;
    int row = blockIdx.x;
    const float4* xr = (const float4*)(x + (size_t)row * 2048);
    float4 a = xr[t * 2];
    float4 b = xr[t * 2 + 1];
    float f[8] = {a.x, a.y, a.z, a.w, b.x, b.y, b.z, b.w};
    float m = 0.f;
#pragma unroll
    for (int k = 0; k < 8; ++k) m = fmaxf(m, fabsf(f[k]));
    red[t] = m;
    __syncthreads();
    for (int o = 128; o > 0; o >>= 1) {
        if (t < o) red[t] = fmaxf(red[t], red[t + o]);
        __syncthreads();
    }
    float mx = fmaxf(red[0], 1e-5f);
    float s = 127.f / mx;
    unsigned int lo = 0, hi = 0;
#pragma unroll
    for (int k = 0; k < 4; ++k) {
        int qv = (int)fminf(fmaxf(rintf(f[k] * s), -128.f), 127.f);
        lo |= ((unsigned int)(qv & 0xff)) << (8 * k);
    }
#pragma unroll
    for (int k = 0; k < 4; ++k) {
        int qv = (int)fminf(fmaxf(rintf(f[4 + k] * s), -128.f), 127.f);
        hi |= ((unsigned int)(qv & 0xff)) << (8 * k);
    }
    uint2 o; o.x = lo; o.y = hi;
    ((uint2*)(qx + (size_t)row * 2048))[t] = o;
    if (t == 0) c1[row] = (float)((accw[0] * INV_WELEMS + 1e-5) / (double)s);
}

// ---- int8 GEMM, BMxBN tile, BK=128, global_load_lds + XOR-swizzled LDS ----
// EPI=0: H16[m,n] = sat16(relu(acc)), rmax[m] = atomicMax row max (int).
// EPI=1: Oout[m,n] = acc * rs[m]  (fp32).
// Waves: 2(m) x 2(n); wave-tile (BM/2) x (BN/2).
template <int EPI, int BM, int BN>
__global__ __launch_bounds__(256) void gemm_i8_kernel(
    const int8_t* __restrict__ A, const int8_t* __restrict__ B,
    const float* __restrict__ rs, short* __restrict__ H16,
    int* __restrict__ rmax, float* __restrict__ Oout,
    int N, int K) {
    constexpr int WM = BM / 2, WN = BN / 2;
    constexpr int MI = WM / 16, NI = WN / 16;
    constexpr int AISS = BM / 32, BISS = BN / 32;
    __shared__ __align__(16) int8_t sA[BM * 128];
    __shared__ __align__(16) int8_t sB[BN * 128];
    int t = threadIdx.x;
    int wid = t >> 6;
    int lane = t & 63;
    int lrow = lane & 15, g = lane >> 4;

    // XCD-aware remap: xcd c = f&7 owns n-tiles [c*npc, (c+1)*npc); n inner, m outer.
    int f = blockIdx.y * gridDim.x + blockIdx.x;
    int npc = gridDim.x >> 3;
    int c8 = f & 7, j = f >> 3;
    int nt = c8 * npc + (j % npc);
    int mt = j / npc;
    int m0 = mt * BM, n0 = nt * BN;

    int wm = (wid & 1) * WM, wn = (wid >> 1) * WN;

    v4i acc[MI][NI];
#pragma unroll
    for (int i = 0; i < MI; ++i)
#pragma unroll
        for (int jn = 0; jn < NI; ++jn) acc[i][jn] = (v4i){0, 0, 0, 0};

    // staging: issue i of wave w covers LDS rows [(i*4+w)*8, +8), lane l -> row +(l>>3),
    // phys 16B-chunk (l&7). Inverse-swizzled global source chunk = (l&7)^(l>>3).
    int srow = lane >> 3;
    int schunk = ((lane & 7) ^ (lane >> 3)) << 4;
    const int8_t* gA = A + (size_t)(m0 + srow) * K + schunk;
    const int8_t* gB = B + (size_t)(n0 + srow) * K + schunk;

    // fragment read byte offsets (swizzled): row*128 + (((kk*4+g)^(lrow&7))<<4)
    int swz = lrow & 7;

    for (int k = 0; k < K; k += 128) {
#pragma unroll
        for (int i = 0; i < AISS; ++i)
            async_ld16(gA + k + (size_t)((i * 4 + wid) * 8) * K,
                       sA + (i * 4 + wid) * 1024);
#pragma unroll
        for (int i = 0; i < BISS; ++i)
            async_ld16(gB + k + (size_t)((i * 4 + wid) * 8) * K,
                       sB + (i * 4 + wid) * 1024);
        __syncthreads();
#pragma unroll
        for (int kk = 0; kk < 2; ++kk) {
            v4i af[MI], bfr[NI];
            int co = ((kk * 4 + g) ^ swz) << 4;
#pragma unroll
            for (int i = 0; i < MI; ++i)
                af[i] = *(const v4i*)(sA + (wm + i * 16 + lrow) * 128 + co);
#pragma unroll
            for (int jn = 0; jn < NI; ++jn)
                bfr[jn] = *(const v4i*)(sB + (wn + jn * 16 + lrow) * 128 + co);
#pragma unroll
            for (int i = 0; i < MI; ++i)
#pragma unroll
                for (int jn = 0; jn < NI; ++jn)
                    acc[i][jn] = __builtin_amdgcn_mfma_i32_16x16x64_i8(
                        af[i], bfr[jn], acc[i][jn], 0, 0, 0);
        }
        __syncthreads();
    }

#pragma unroll
    for (int i = 0; i < MI; ++i) {
#pragma unroll
        for (int r = 0; r < 4; ++r) {
            int gm = m0 + wm + i * 16 + g * 4 + r;
            if (EPI == 0) {
                int rmx = 0;
#pragma unroll
                for (int jn = 0; jn < NI; ++jn) {
                    int v = acc[i][jn][r];
                    int a = v > 0 ? v : 0;
                    a = a > 32767 ? 32767 : a;
                    rmx = a > rmx ? a : rmx;
                    H16[(size_t)gm * N + (n0 + wn + jn * 16 + lrow)] = (short)a;
                }
                rmx = max(rmx, __shfl_xor(rmx, 1));
                rmx = max(rmx, __shfl_xor(rmx, 2));
                rmx = max(rmx, __shfl_xor(rmx, 4));
                rmx = max(rmx, __shfl_xor(rmx, 8));
                if (lrow == 0) atomicMax(&rmax[gm], rmx);
            } else {
                float cc = rs[gm];
#pragma unroll
                for (int jn = 0; jn < NI; ++jn) {
                    int gn = n0 + wn + jn * 16 + lrow;
                    Oout[(size_t)gm * N + gn] = (float)acc[i][jn][r] * cc;
                }
            }
        }
    }
}

// ---- per-row scale from int rowmax: s = 127/max((rmax*c1)^2, 1e-5) --------
__global__ void scale_kernel(const int* __restrict__ rmax,
                             const float* __restrict__ c1r,
                             const double* __restrict__ accw,
                             float* __restrict__ sArr,
                             float* __restrict__ c2Arr, int CR) {
    int i = blockIdx.x * 256 + threadIdx.x;
    if (i >= CR) return;
    float v = (float)rmax[i] * c1r[i];
    float mx = fmaxf(v * v, 1e-5f);
    float s = 127.f / mx;
    sArr[i] = s;
    c2Arr[i] = (float)((accw[0] * INV_WELEMS + 1e-5) / (double)s);
}

// ---- quantize h: qh = rint(((a*c1)^2) * s), a = int16 relu acc ------------
__global__ void quant_h_kernel(const short* __restrict__ H,
                               int8_t* __restrict__ qh,
                               const float* __restrict__ sArr,
                               const float* __restrict__ c1r) {
    int t = threadIdx.x;
    int row = blockIdx.x;
    float s = sArr[row];
    float c1m = c1r[row];
    const short8* hr = (const short8*)(H + (size_t)row * 8192);
    uint2* qr = (uint2*)(qh + (size_t)row * 8192);
#pragma unroll
    for (int it = 0; it < 4; ++it) {
        short8 v = hr[it * 256 + t];
        unsigned int lo = 0, hi = 0;
#pragma unroll
        for (int e = 0; e < 4; ++e) {
            float x = (float)v[e] * c1m;
            int q = (int)rintf(fminf(x * x * s, 127.f));
            lo |= ((unsigned int)(q & 0xff)) << (8 * e);
        }
#pragma unroll
        for (int e = 0; e < 4; ++e) {
            float x = (float)v[4 + e] * c1m;
            int q = (int)rintf(fminf(x * x * s, 127.f));
            hi |= ((unsigned int)(q & 0xff)) << (8 * e);
        }
        uint2 o; o.x = lo; o.y = hi;
        qr[it * 256 + t] = o;
    }
}

extern "C" void kernel_launch(void* const* d_in, const int* in_sizes, int n_in,
                              void* d_out, int out_size, void* d_ws, size_t ws_size,
                              hipStream_t stream) {
    const float* x  = (const float*)d_in[0];
    const float* w1 = (const float*)d_in[1];
    const float* w2 = (const float*)d_in[2];
    float* out = (float*)d_out;

    char* p = (char*)d_ws;
    double* accs = (double*)p;                         // [0]=sum|w1| [1]=sum|w2|
    int8_t* qx  = (int8_t*)(p + (1ull << 20));         // 16 MB
    int8_t* qw1 = qx + (16ull << 20);                  // 16 MB
    int8_t* qw2 = qw1 + (16ull << 20);                 // 16 MB
    float* c1   = (float*)(p + (49ull << 20));         // 32 KB
    float* sArr = c1 + 8192;                           // 32 KB
    float* c2Arr = sArr + 8192;                        // 32 KB
    int*   rmaxI = (int*)(c2Arr + 8192);               // 32 KB
    char* varbase = p + (50ull << 20);

    // adaptive M-chunking: int16 H (CR x 8192 x 2B) + int8 qh (CR x 8192)
    int nchunk = 1;
    while (nchunk <= 64 &&
           (50ull << 20) + (size_t)(8192 / nchunk) * 24576ull > ws_size)
        nchunk <<= 1;
    if (nchunk > 64) return;  // workspace too small — fail loudly
    int CR = 8192 / nchunk;
    short* H = (short*)varbase;                        // CR x 8192 int16
    int8_t* qh = (int8_t*)(varbase + (size_t)CR * 8192 * 2);

    hipMemsetAsync(p, 0, 256, stream);
    absmean_kernel<<<4096, 256, 0, stream>>>(w1, accs + 0);
    absmean_kernel<<<4096, 256, 0, stream>>>(w2, accs + 1);
    quant_w_kernel<<<8192, 256, 0, stream>>>(w1, qw1, accs + 0);
    quant_w_kernel<<<8192, 256, 0, stream>>>(w2, qw2, accs + 1);
    quant_x_kernel<<<8192, 256, 0, stream>>>(x, qx, c1, accs + 0);

    for (int cs = 0; cs < 8192; cs += CR) {
        hipMemsetAsync(rmaxI, 0, (size_t)CR * sizeof(int), stream);
        gemm_i8_kernel<0, 128, 128><<<dim3(64, CR / 128), 256, 0, stream>>>(
            qx + (size_t)cs * 2048, qw1, nullptr, H, rmaxI, nullptr, 8192, 2048);
        scale_kernel<<<(CR + 255) / 256, 256, 0, stream>>>(
            rmaxI, c1 + cs, accs + 1, sArr, c2Arr, CR);
        quant_h_kernel<<<CR, 256, 0, stream>>>(H, qh, sArr, c1 + cs);
        gemm_i8_kernel<1, 64, 128><<<dim3(16, CR / 64), 256, 0, stream>>>(
            qh, qw2, c2Arr, nullptr, nullptr, out + (size_t)cs * 2048, 2048, 8192);
    }
}

// Round 2
// 589.732 us; speedup vs baseline: 1.2954x; 1.1360x over previous
//
#include <hip/hip_runtime.h>
#include <cstdint>
#include <cstddef>

// BitNet b1.58 FFN: x[8192,2048] fp32 -> h[8192,8192] (relu^2) -> out[8192,2048] fp32
// R6: 8-phase counted-vmcnt 256x256 GEMM (T3+T4+T2+T5 port of the m201 template to i8).
//     BK=128, 8 waves (2Mx4N), 128KB LDS double-buffer, band-organized LDS so staging
//     units == freed regions. vmcnt(6) only at phases 4/8. B-frags register-cached.
//     scale_kernel fused into quant_h. Numerics op-identical to R5 (absmax 0.015625).

typedef int v4i __attribute__((ext_vector_type(4)));
typedef short short8 __attribute__((ext_vector_type(8)));

#define INV_WELEMS (1.0 / 16777216.0)   // 1 / (8192*2048)

__device__ __forceinline__ void async_ld16(const void* g, void* s) {
    __builtin_amdgcn_global_load_lds(
        (const __attribute__((address_space(1))) void*)(uintptr_t)g,
        (__attribute__((address_space(3))) void*)(unsigned int)(uintptr_t)s,
        16, 0, 0);
}

// ---- sum(|w|) over 16.7M fp32, fp64 accumulate ----------------------------
__global__ void absmean_kernel(const float* __restrict__ w,
                               double* __restrict__ acc) {
    __shared__ double red[256];
    int t = threadIdx.x;
    unsigned int tid = blockIdx.x * 256u + t;
    const float4* wv = (const float4*)w;
    float s = 0.f;
#pragma unroll
    for (int i = 0; i < 4; ++i) {
        float4 v = wv[tid + i * 1048576u];
        s += fabsf(v.x) + fabsf(v.y) + fabsf(v.z) + fabsf(v.w);
    }
    red[t] = (double)s;
    __syncthreads();
    for (int o = 128; o > 0; o >>= 1) {
        if (t < o) red[t] += red[t + o];
        __syncthreads();
    }
    if (t == 0) atomicAdd(acc, red[0]);
}

// ---- ternary quantize weights: q = clip(rint(w/gamma), -1, 1) -------------
__global__ void quant_w_kernel(const float* __restrict__ w,
                               int8_t* __restrict__ q,
                               const double* __restrict__ acc) {
    float gamma = (float)(acc[0] * INV_WELEMS + 1e-5);
    unsigned int tid = blockIdx.x * 256u + threadIdx.x;
    const float4* wv = (const float4*)w;
    float4 a = wv[tid * 2];
    float4 b = wv[tid * 2 + 1];
    float f[8] = {a.x, a.y, a.z, a.w, b.x, b.y, b.z, b.w};
    unsigned int lo = 0, hi = 0;
#pragma unroll
    for (int k = 0; k < 4; ++k) {
        int qv = (int)fminf(fmaxf(rintf(f[k] / gamma), -1.f), 1.f);
        lo |= ((unsigned int)(qv & 0xff)) << (8 * k);
    }
#pragma unroll
    for (int k = 0; k < 4; ++k) {
        int qv = (int)fminf(fmaxf(rintf(f[4 + k] / gamma), -1.f), 1.f);
        hi |= ((unsigned int)(qv & 0xff)) << (8 * k);
    }
    uint2 o; o.x = lo; o.y = hi;
    ((uint2*)q)[tid] = o;
}

// ---- per-token int8 quantize of x; c1[row] = gamma1 / s -------------------
__global__ void quant_x_kernel(const float* __restrict__ x,
                               int8_t* __restrict__ qx,
                               float* __restrict__ c1,
                               const double* __restrict__ accw) {
    __shared__ float red[256];
    int t = threadIdx.x;
    int row = blockIdx.x;
    const float4* xr = (const float4*)(x + (size_t)row * 2048);
    float4 a = xr[t * 2];
    float4 b = xr[t * 2 + 1];
    float f[8] = {a.x, a.y, a.z, a.w, b.x, b.y, b.z, b.w};
    float m = 0.f;
#pragma unroll
    for (int k = 0; k < 8; ++k) m = fmaxf(m, fabsf(f[k]));
    red[t] = m;
    __syncthreads();
    for (int o = 128; o > 0; o >>= 1) {
        if (t < o) red[t] = fmaxf(red[t], red[t + o]);
        __syncthreads();
    }
    float mx = fmaxf(red[0], 1e-5f);
    float s = 127.f / mx;
    unsigned int lo = 0, hi = 0;
#pragma unroll
    for (int k = 0; k < 4; ++k) {
        int qv = (int)fminf(fmaxf(rintf(f[k] * s), -128.f), 127.f);
        lo |= ((unsigned int)(qv & 0xff)) << (8 * k);
    }
#pragma unroll
    for (int k = 0; k < 4; ++k) {
        int qv = (int)fminf(fmaxf(rintf(f[4 + k] * s), -128.f), 127.f);
        hi |= ((unsigned int)(qv & 0xff)) << (8 * k);
    }
    uint2 o; o.x = lo; o.y = hi;
    ((uint2*)(qx + (size_t)row * 2048))[t] = o;
    if (t == 0) c1[row] = (float)((accw[0] * INV_WELEMS + 1e-5) / (double)s);
}

// ---- 8-phase 256x256 int8 GEMM, BK=128, counted vmcnt ---------------------
// LDS per tile-buffer: A 32KB [qm][wm][64 rows][128B], B 32KB [qn][wn][32 rows][128B].
// 2 buffers (even/odd K-tiles) = 128KB. Quadrant order (0,0)(0,1)(1,1)(1,0),
// B-frags register-cached so B0 frees after ph1.
// Steady-state stages: ph1 A1(t+1)->buf1, ph2 B0(t+2)->buf0, ph3 A0(t+2)->buf0,
// ph4 B1(t+2)->buf0 +vmcnt(6), ph5 A1(t+2)->buf0, ph6 B0(t+3)->buf1,
// ph7 A0(t+3)->buf1, ph8 B1(t+3)->buf1 +vmcnt(6).
// vmcnt(6) at ph4 guarantees through ph1's stage (tile t+1 complete for ph5-8);
// vmcnt(6) at ph8 guarantees through ph5's stage (tile t+2 complete for next iter).
// EPI=0: H16 = sat16(relu(acc)); rmax[m] = atomicMax. EPI=1: Oout = acc*rs[m].
template <int EPI>
__global__ __launch_bounds__(512, 2) void gemm8_i8(
    const int8_t* __restrict__ A, const int8_t* __restrict__ B,
    const float* __restrict__ rs, short* __restrict__ H16,
    int* __restrict__ rmax, float* __restrict__ Oout, int N, int K) {
    extern __shared__ __align__(16) int8_t smem[];
    int8_t* sA = smem;           // 2 x 32KB
    int8_t* sB = smem + 65536;   // 2 x 32KB

    int t = threadIdx.x;
    int wid = t >> 6;
    int lane = t & 63;
    int lrow = lane & 15, g = lane >> 4, swz = lrow & 7;
    int wm2 = wid >> 2, wn2 = wid & 3;
    int srow = lane >> 3;
    int schunk = ((lane & 7) ^ (lane >> 3)) << 4;

    // XCD remap: xcd c = f&7 owns n-tile slice; n-inner, m-outer within XCD.
    int f = blockIdx.y * gridDim.x + blockIdx.x;
    int npc = gridDim.x >> 3;
    int c8 = f & 7, jj = f >> 3;
    int nt = c8 * npc + (jj % npc);
    int mt = jj / npc;
    int m0 = mt * 256, n0 = nt * 256;

    const int8_t* gAptr = A + (size_t)(m0 + wid * 8 + srow) * K + schunk;
    const int8_t* gBptr = B + (size_t)(n0 + (wid >> 2) * 64 + (wid & 3) * 8 + srow) * K + schunk;

    v4i acc[8][4];
#pragma unroll
    for (int i = 0; i < 8; ++i)
#pragma unroll
        for (int j2 = 0; j2 < 4; ++j2) acc[i][j2] = (v4i){0, 0, 0, 0};

#define STAGE_A(buf, qm, ko) do { \
    async_ld16(gAptr + (qm) * 64 * K + (ko), sA + (buf) * 32768 + (qm) * 16384 + wid * 1024); \
    async_ld16(gAptr + ((qm) * 64 + 128) * K + (ko), sA + (buf) * 32768 + (qm) * 16384 + 8192 + wid * 1024); \
} while (0)

#define STAGE_B(buf, qn, ko) do { \
    async_ld16(gBptr + (qn) * 32 * K + (ko), sB + (buf) * 32768 + (qn) * 16384 + wid * 1024); \
    async_ld16(gBptr + ((qn) * 32 + 128) * K + (ko), sB + (buf) * 32768 + (qn) * 16384 + 8192 + wid * 1024); \
} while (0)

#define LDA4(buf, qm) do { \
    const int8_t* ap_ = sA + (buf) * 32768 + (qm) * 16384 + wm2 * 8192 + lrow * 128; \
    _Pragma("unroll") for (int i_ = 0; i_ < 4; ++i_) { \
        af[i_][0] = *(const v4i*)(ap_ + i_ * 2048 + ((g ^ swz) << 4)); \
        af[i_][1] = *(const v4i*)(ap_ + i_ * 2048 + (((4 + g) ^ swz) << 4)); } \
} while (0)

#define LDB4(dst, buf, qn) do { \
    const int8_t* bp_ = sB + (buf) * 32768 + (qn) * 16384 + wn2 * 4096 + lrow * 128; \
    _Pragma("unroll") for (int jn_ = 0; jn_ < 2; ++jn_) { \
        dst[jn_][0] = *(const v4i*)(bp_ + jn_ * 2048 + ((g ^ swz) << 4)); \
        dst[jn_][1] = *(const v4i*)(bp_ + jn_ * 2048 + (((4 + g) ^ swz) << 4)); } \
} while (0)

#define MM(qm, qn, bfrag) do { \
    __builtin_amdgcn_s_setprio(1); \
    _Pragma("unroll") for (int i_ = 0; i_ < 4; ++i_) \
    _Pragma("unroll") for (int jn_ = 0; jn_ < 2; ++jn_) { \
        acc[(qm) * 4 + i_][(qn) * 2 + jn_] = __builtin_amdgcn_mfma_i32_16x16x64_i8( \
            af[i_][0], bfrag[jn_][0], acc[(qm) * 4 + i_][(qn) * 2 + jn_], 0, 0, 0); \
        acc[(qm) * 4 + i_][(qn) * 2 + jn_] = __builtin_amdgcn_mfma_i32_16x16x64_i8( \
            af[i_][1], bfrag[jn_][1], acc[(qm) * 4 + i_][(qn) * 2 + jn_], 0, 0, 0); } \
    __builtin_amdgcn_s_setprio(0); \
} while (0)

#define BAR() __builtin_amdgcn_s_barrier()
#define LGKM0() do { asm volatile("s_waitcnt lgkmcnt(0)" ::: "memory"); \
                     __builtin_amdgcn_sched_barrier(0); } while (0)
#define VMC6() do { asm volatile("s_waitcnt vmcnt(6)" ::: "memory"); } while (0)

    int NT = K >> 7;
    int kmask = K - 1;
#define KT(x) (((x) << 7) & kmask)

    // prologue: B0(0) A0(0) B1(0) A1(0) B0(1) A0(1) B1(1)  (14 loads; allow last 6)
    STAGE_B(0, 0, 0); STAGE_A(0, 0, 0); STAGE_B(0, 1, 0); STAGE_A(0, 1, 0);
    STAGE_B(1, 0, KT(1)); STAGE_A(1, 0, KT(1)); STAGE_B(1, 1, KT(1));
    VMC6();
    BAR();

    v4i af[4][2], b0[2][2], b1[2][2];

    for (int it = 0; it < (NT >> 1); ++it) {
        int tt = it * 2;
        int k1 = KT(tt + 1), k2 = KT(tt + 2), k3 = KT(tt + 3);

        // ph1: even tile quad(0,0); stage A1(t+1)->buf1
        LDA4(0, 0); LDB4(b0, 0, 0);
        STAGE_A(1, 1, k1);
        BAR(); LGKM0();
        MM(0, 0, b0);
        BAR();

        // ph2: quad(0,1); stage B0(t+2)->buf0 (B0 freed: reg-cached since ph1)
        LDB4(b1, 0, 1);
        STAGE_B(0, 0, k2);
        BAR(); LGKM0();
        MM(0, 1, b1);
        BAR();

        // ph3: quad(1,1); stage A0(t+2)->buf0 (A0 last read ph1)
        LDA4(0, 1);
        STAGE_A(0, 0, k2);
        BAR(); LGKM0();
        MM(1, 1, b1);
        BAR();

        // ph4: quad(1,0) from regs; stage B1(t+2)->buf0; counted vmcnt
        STAGE_B(0, 1, k2);
        BAR(); __builtin_amdgcn_sched_barrier(0);
        MM(1, 0, b0);
        VMC6();
        BAR();

        // ph5: odd tile quad(0,0); stage A1(t+2)->buf0 (A1 last read ph4... ph3 reads, ph4 regs)
        LDA4(1, 0); LDB4(b0, 1, 0);
        STAGE_A(0, 1, k2);
        BAR(); LGKM0();
        MM(0, 0, b0);
        BAR();

        // ph6: quad(0,1); stage B0(t+3)->buf1
        LDB4(b1, 1, 1);
        STAGE_B(1, 0, k3);
        BAR(); LGKM0();
        MM(0, 1, b1);
        BAR();

        // ph7: quad(1,1); stage A0(t+3)->buf1
        LDA4(1, 1);
        STAGE_A(1, 0, k3);
        BAR(); LGKM0();
        MM(1, 1, b1);
        BAR();

        // ph8: quad(1,0) from regs; stage B1(t+3)->buf1; counted vmcnt
        STAGE_B(1, 1, k3);
        BAR(); __builtin_amdgcn_sched_barrier(0);
        MM(1, 0, b0);
        VMC6();
        BAR();
    }

    // ---- epilogue: C rows = m0 + wm2*128 + fi*16 + g*4 + r; cols = n0 + wn2*64 + fj*16 + lrow
    if (EPI == 0) {
#pragma unroll
        for (int fi = 0; fi < 8; ++fi) {
#pragma unroll
            for (int r = 0; r < 4; ++r) {
                int gm = m0 + wm2 * 128 + fi * 16 + g * 4 + r;
                short* hrow = H16 + (size_t)gm * N + n0 + wn2 * 64;
                int rmx = 0;
#pragma unroll
                for (int fj = 0; fj < 4; ++fj) {
                    int v = acc[fi][fj][r];
                    int a = v > 0 ? v : 0;
                    a = a > 32767 ? 32767 : a;
                    rmx = a > rmx ? a : rmx;
                    hrow[fj * 16 + lrow] = (short)a;
                }
                rmx = max(rmx, __shfl_xor(rmx, 1));
                rmx = max(rmx, __shfl_xor(rmx, 2));
                rmx = max(rmx, __shfl_xor(rmx, 4));
                rmx = max(rmx, __shfl_xor(rmx, 8));
                if (lrow == 0) atomicMax(&rmax[gm], rmx);
            }
        }
    } else {
#pragma unroll
        for (int fi = 0; fi < 8; ++fi) {
#pragma unroll
            for (int r = 0; r < 4; ++r) {
                int gm = m0 + wm2 * 128 + fi * 16 + g * 4 + r;
                float cc = rs[gm];
                float* orow = Oout + (size_t)gm * N + n0 + wn2 * 64;
#pragma unroll
                for (int fj = 0; fj < 4; ++fj)
                    orow[fj * 16 + lrow] = (float)acc[fi][fj][r] * cc;
            }
        }
    }
#undef STAGE_A
#undef STAGE_B
#undef LDA4
#undef LDB4
#undef MM
#undef BAR
#undef LGKM0
#undef VMC6
#undef KT
}

// ---- fused per-row scale + int8 quantize of h -----------------------------
// s = 127/max((rmax*c1)^2, 1e-5);  qh = rint(min((a*c1)^2 * s, 127));  c2 = gamma2/s
__global__ void quant_h_kernel(const short* __restrict__ H,
                               int8_t* __restrict__ qh,
                               const int* __restrict__ rmax,
                               const float* __restrict__ c1r,
                               float* __restrict__ c2Arr,
                               const double* __restrict__ accw) {
    int t = threadIdx.x;
    int row = blockIdx.x;
    float c1m = c1r[row];
    float v = (float)rmax[row] * c1m;
    float mx = fmaxf(v * v, 1e-5f);
    float s = 127.f / mx;
    if (t == 0) c2Arr[row] = (float)((accw[0] * INV_WELEMS + 1e-5) / (double)s);
    const short8* hr = (const short8*)(H + (size_t)row * 8192);
    uint2* qr = (uint2*)(qh + (size_t)row * 8192);
#pragma unroll
    for (int it = 0; it < 4; ++it) {
        short8 vv = hr[it * 256 + t];
        unsigned int lo = 0, hi = 0;
#pragma unroll
        for (int e = 0; e < 4; ++e) {
            float x = (float)vv[e] * c1m;
            int q = (int)rintf(fminf(x * x * s, 127.f));
            lo |= ((unsigned int)(q & 0xff)) << (8 * e);
        }
#pragma unroll
        for (int e = 0; e < 4; ++e) {
            float x = (float)vv[4 + e] * c1m;
            int q = (int)rintf(fminf(x * x * s, 127.f));
            hi |= ((unsigned int)(q & 0xff)) << (8 * e);
        }
        uint2 o; o.x = lo; o.y = hi;
        qr[it * 256 + t] = o;
    }
}

extern "C" void kernel_launch(void* const* d_in, const int* in_sizes, int n_in,
                              void* d_out, int out_size, void* d_ws, size_t ws_size,
                              hipStream_t stream) {
    const float* x  = (const float*)d_in[0];
    const float* w1 = (const float*)d_in[1];
    const float* w2 = (const float*)d_in[2];
    float* out = (float*)d_out;

    static bool attr_set = false;
    if (!attr_set) {
        hipFuncSetAttribute((const void*)gemm8_i8<0>,
                            hipFuncAttributeMaxDynamicSharedMemorySize, 131072);
        hipFuncSetAttribute((const void*)gemm8_i8<1>,
                            hipFuncAttributeMaxDynamicSharedMemorySize, 131072);
        attr_set = true;
    }

    char* p = (char*)d_ws;
    double* accs = (double*)p;                         // [0]=sum|w1| [1]=sum|w2|
    int8_t* qx  = (int8_t*)(p + (1ull << 20));         // 16 MB
    int8_t* qw1 = qx + (16ull << 20);                  // 16 MB
    int8_t* qw2 = qw1 + (16ull << 20);                 // 16 MB
    float* c1    = (float*)(p + (49ull << 20));        // 32 KB
    float* c2Arr = c1 + 8192;                          // 32 KB
    int*   rmaxI = (int*)(c2Arr + 8192);               // 32 KB
    char* varbase = p + (50ull << 20);

    // adaptive M-chunking: int16 H (CR x 8192 x 2B) + int8 qh (CR x 8192)
    int nchunk = 1;
    while (nchunk <= 32 &&
           (50ull << 20) + (size_t)(8192 / nchunk) * 24576ull > ws_size)
        nchunk <<= 1;
    if (nchunk > 32) return;  // workspace too small — fail loudly
    int CR = 8192 / nchunk;
    short* H = (short*)varbase;                        // CR x 8192 int16
    int8_t* qh = (int8_t*)(varbase + (size_t)CR * 8192 * 2);

    hipMemsetAsync(p, 0, 256, stream);
    absmean_kernel<<<4096, 256, 0, stream>>>(w1, accs + 0);
    absmean_kernel<<<4096, 256, 0, stream>>>(w2, accs + 1);
    quant_w_kernel<<<8192, 256, 0, stream>>>(w1, qw1, accs + 0);
    quant_w_kernel<<<8192, 256, 0, stream>>>(w2, qw2, accs + 1);
    quant_x_kernel<<<8192, 256, 0, stream>>>(x, qx, c1, accs + 0);

    for (int cs = 0; cs < 8192; cs += CR) {
        hipMemsetAsync(rmaxI, 0, (size_t)CR * sizeof(int), stream);
        gemm8_i8<0><<<dim3(32, CR / 256), 512, 131072, stream>>>(
            qx + (size_t)cs * 2048, qw1, nullptr, H, rmaxI, nullptr, 8192, 2048);
        quant_h_kernel<<<CR, 256, 0, stream>>>(H, qh, rmaxI, c1 + cs, c2Arr, accs + 1);
        gemm8_i8<1><<<dim3(8, CR / 256), 512, 131072, stream>>>(
            qh, qw2, c2Arr, nullptr, nullptr, out + (size_t)cs * 2048, 2048, 8192);
    }
}